// Round 9
// baseline (323.471 us; speedup 1.0000x reference)
//
#include <hip/hip_runtime.h>
#include <hip/hip_bf16.h>

// RNN wavefunction log-prob: N=128, B=8192, H=128, D=2 (one-hot). f32 in/out.
// R9: 512 blocks x 128 threads (2 waves). Each wave owns 64 of 128 columns;
// ALL weights in VGPRs (192/wave). 1 wave/SIMD, 512-VGPR budget.
// Minimal LDS: h-state exchange only (8 b128 reads + 8 b64 writes per wave
// per iter), one 2-wave barrier per step. Masks+biases in registers.
// a1 split into two depth-4 MFMA chains. Logits duty alternates waves.

#define NSTEP 128
#define BTOT  8192
#define HID   128
#define MB    16
#define NBLK  (BTOT / MB)   // 512
#define NTHR  128

typedef __attribute__((ext_vector_type(8))) short bf16x8;
typedef __attribute__((ext_vector_type(4))) float f32x4;
typedef __attribute__((ext_vector_type(2))) float f32x2;
typedef __attribute__((ext_vector_type(2))) unsigned uint32x2;

__device__ __forceinline__ short f2bf(float v) {
    unsigned u = __builtin_bit_cast(unsigned, v);
    u += 0x7FFFu + ((u >> 16) & 1u);
    return (short)(u >> 16);
}
__device__ __forceinline__ unsigned cvt2bf(float a, float b) {
    __hip_bfloat162 h2 = __float22bfloat162_rn(make_float2(a, b));
    unsigned u; __builtin_memcpy(&u, &h2, sizeof(u));
    return u;
}
// tanh on a pair: 2 exp + ONE rcp (shared via rcp(d0*d1))
__device__ __forceinline__ f32x2 tanh2(f32x2 x) {
    f32x2 z = x * 2.885390081777927f;            // 2x*log2(e)
    float e0 = __builtin_exp2f(z.x);
    float e1 = __builtin_exp2f(z.y);
    f32x2 d = {e0 + 1.0f, e1 + 1.0f};
    float r = __builtin_amdgcn_rcpf(d.x * d.y);
    f32x2 inv = {r * d.y, r * d.x};
    return inv * -2.0f + 1.0f;
}

__global__ __launch_bounds__(NTHR, 1) void rnn_wf_kernel(
    const float* __restrict__ samples,  // (128, 8192, 2)
    const float* __restrict__ Wih0,     // (128, 2)
    const float* __restrict__ bih0,     // (128,)
    const float* __restrict__ Whh0,     // (128, 128)
    const float* __restrict__ bhh0,     // (128,)
    const float* __restrict__ Wih1,     // (128, 128)
    const float* __restrict__ bih1,     // (128,)
    const float* __restrict__ Whh1,     // (128, 128)
    const float* __restrict__ bhh1,     // (128,)
    const float* __restrict__ Wd,       // (2, 128)
    const float* __restrict__ bd,       // (2,)
    float* __restrict__ out)            // (1, 8192)
{
    __shared__ short sH0[2][MB * HID];
    __shared__ short sH1[2][MB * HID];
    __shared__ unsigned sMask[NSTEP];
    __shared__ float sLd[NSTEP * 17];   // logit diffs [t*17 + s]

    const int tid  = threadIdx.x;
    const int b0   = blockIdx.x * MB;
    const int W    = tid >> 6;          // wave 0/1, owns n in [64W, 64W+64)
    const int lane = tid & 63;
    const int q    = lane >> 4;
    const int c    = lane & 15;
    const int nb   = W * 64;

    // ---- decode one-hot -> per-step 16-bit masks (one thread per step) ----
    {
        unsigned msk = 0;
        for (int m = 0; m < MB; ++m) {
            float e1 = samples[((size_t)tid * BTOT + b0 + m) * 2 + 1];
            if (e1 > 0.5f) msk |= (1u << m);
        }
        sMask[tid] = msk;
    }

    // ---- weights -> A-frags in registers: [nt][kb], n = nb+16nt+c ----
    bf16x8 fhh0[4][4], fih1[4][4], fhh1[4][4];
    #pragma unroll
    for (int nt = 0; nt < 4; ++nt) {
        const int nn = nb + nt * 16 + c;
        #pragma unroll
        for (int kb = 0; kb < 4; ++kb) {
            const int off = nn * HID + kb * 32 + q * 8;
            bf16x8 v0, v1, v2;
            #pragma unroll
            for (int j = 0; j < 8; ++j) {
                v0[j] = f2bf(Whh0[off + j]);
                v1[j] = f2bf(Wih1[off + j]);
                v2[j] = f2bf(Whh1[off + j]);
            }
            fhh0[nt][kb] = v0; fih1[nt][kb] = v1; fhh1[nt][kb] = v2;
        }
    }
    bf16x8 fwd[4];                      // dense head rows 0,1; rows>=2 zero
    #pragma unroll
    for (int kb = 0; kb < 4; ++kb) {
        bf16x8 v;
        #pragma unroll
        for (int j = 0; j < 8; ++j)
            v[j] = (c < 2) ? f2bf(Wd[c * HID + kb * 32 + q * 8 + j]) : (short)0;
        fwd[kb] = v;
    }
    // ---- biases in registers: index [nt][r], n = nb+16nt+4q+r ----
    f32x4 pA[4], pB[4], b1v[4], b0v[4];
    #pragma unroll
    for (int nt = 0; nt < 4; ++nt)
        #pragma unroll
        for (int r = 0; r < 4; ++r) {
            const int n = nb + nt * 16 + q * 4 + r;
            const float bb = bih0[n] + bhh0[n];
            b0v[nt][r] = bb;
            pA[nt][r]  = bb + Wih0[n * 2 + 0];
            pB[nt][r]  = bb + Wih0[n * 2 + 1];
            b1v[nt][r] = bih1[n] + bhh1[n];
        }
    const float bd0 = bd[0], bd1 = bd[1];

    // ---- t-invariant LDS indices (halfwords), full-c XOR swizzle ----
    int ra[4];
    #pragma unroll
    for (int kb = 0; kb < 4; ++kb)
        ra[kb] = c * HID + (((kb * 4 + q) ^ c) << 3);
    int wa[4];                          // write addr per n-tile
    #pragma unroll
    for (int nt = 0; nt < 4; ++nt)
        wa[nt] = c * HID + ((((W << 3) + (nt << 1) + (q >> 1)) ^ c) << 3)
               + ((q & 1) << 2);

    __syncthreads();                    // sMask published

    // ---- pre-pack this lane's sample-c mask bits: 128 steps -> 4 dwords ----
    unsigned mw[4] = {0, 0, 0, 0};
    for (int t = 0; t < NSTEP; ++t)
        mw[t >> 5] |= ((sMask[t] >> c) & 1u) << (t & 31);

    auto storeL = [&](short* buf, const f32x4* a) {
        #pragma unroll
        for (int nt = 0; nt < 4; ++nt) {
            f32x2 t0 = tanh2((f32x2){a[nt][0], a[nt][1]});
            f32x2 t1 = tanh2((f32x2){a[nt][2], a[nt][3]});
            uint32x2 v = {cvt2bf(t0.x, t0.y), cvt2bf(t1.x, t1.y)};
            *reinterpret_cast<uint32x2*>(&buf[wa[nt]]) = v;
        }
    };

    bool bmPrev = false;

    // ---- i = 0: h0(0) = tanh(b0) ----
    {
        f32x4 a[4] = {b0v[0], b0v[1], b0v[2], b0v[3]};
        storeL(sH0[1], a);
    }
    __syncthreads();

    // ---- i = 1: h0(1), h1(0) = tanh(Wih1 h0(0) + b1) ----
    {
        const bool bm = mw[0] & 1u;
        bf16x8 f0[4];
        #pragma unroll
        for (int kb = 0; kb < 4; ++kb)
            f0[kb] = *reinterpret_cast<const bf16x8*>(&sH0[1][ra[kb]]);
        f32x4 a0[4], a1[4];
        #pragma unroll
        for (int nt = 0; nt < 4; ++nt) {
            a0[nt] = bm ? pB[nt] : pA[nt];
            a1[nt] = b1v[nt];
            #pragma unroll
            for (int kb = 0; kb < 4; ++kb) {
                a0[nt] = __builtin_amdgcn_mfma_f32_16x16x32_bf16(fhh0[nt][kb], f0[kb], a0[nt], 0, 0, 0);
                a1[nt] = __builtin_amdgcn_mfma_f32_16x16x32_bf16(fih1[nt][kb], f0[kb], a1[nt], 0, 0, 0);
            }
        }
        storeL(sH0[0], a0);
        storeL(sH1[0], a1);
        bmPrev = bm;
        __syncthreads();
    }

    // ---- main: i = 2..127, one 2-wave barrier per iteration ----
    auto stepMain = [&](int i, const short* r0, const short* r1,
                        short* w0b, short* w1b) {
        const bool bm = (mw[(i - 1) >> 5] >> ((i - 1) & 31)) & 1u;
        bf16x8 f0[4], f1[4];
        #pragma unroll
        for (int kb = 0; kb < 4; ++kb) {
            f0[kb] = *reinterpret_cast<const bf16x8*>(&r0[ra[kb]]);
            f1[kb] = *reinterpret_cast<const bf16x8*>(&r1[ra[kb]]);
        }
        f32x4 a0[4], a1a[4], a1b[4];
        #pragma unroll
        for (int nt = 0; nt < 4; ++nt) {
            a0[nt]  = bm ? pB[nt] : pA[nt];
            a1a[nt] = b1v[nt];
            a1b[nt] = {0.f, 0.f, 0.f, 0.f};
            #pragma unroll
            for (int kb = 0; kb < 4; ++kb) {
                a0[nt]  = __builtin_amdgcn_mfma_f32_16x16x32_bf16(fhh0[nt][kb], f0[kb], a0[nt],  0, 0, 0);
                a1a[nt] = __builtin_amdgcn_mfma_f32_16x16x32_bf16(fhh1[nt][kb], f1[kb], a1a[nt], 0, 0, 0);
                a1b[nt] = __builtin_amdgcn_mfma_f32_16x16x32_bf16(fih1[nt][kb], f0[kb], a1b[nt], 0, 0, 0);
            }
        }
        if (W == (i & 1)) {             // alternate logits duty between waves
            f32x4 aL = {bd0, bd1, 0.f, 0.f};
            #pragma unroll
            for (int kb = 0; kb < 4; ++kb)
                aL = __builtin_amdgcn_mfma_f32_16x16x32_bf16(fwd[kb], f1[kb], aL, 0, 0, 0);
            if (q == 0)
                sLd[(i - 2) * 17 + c] = bmPrev ? (aL[0] - aL[1]) : (aL[1] - aL[0]);
        }
        bmPrev = bm;
        f32x4 a1[4];
        #pragma unroll
        for (int nt = 0; nt < 4; ++nt)
            a1[nt] = a1a[nt] + a1b[nt];
        storeL(w0b, a0);                // h0(i)
        storeL(w1b, a1);                // h1(i-1)
        __syncthreads();
    };

    for (int i = 2; i < NSTEP; i += 2) {
        stepMain(i,     sH0[0], sH1[0], sH0[1], sH1[1]);
        stepMain(i + 1, sH0[1], sH1[1], sH0[0], sH1[0]);
    }

    // ---- i = 128: h1(127), logits(126) ----
    {
        bf16x8 f0[4], f1[4];
        #pragma unroll
        for (int kb = 0; kb < 4; ++kb) {
            f0[kb] = *reinterpret_cast<const bf16x8*>(&sH0[0][ra[kb]]);  // h0(127)
            f1[kb] = *reinterpret_cast<const bf16x8*>(&sH1[0][ra[kb]]);  // h1(126)
        }
        f32x4 a1a[4], a1b[4];
        #pragma unroll
        for (int nt = 0; nt < 4; ++nt) {
            a1a[nt] = b1v[nt];
            a1b[nt] = {0.f, 0.f, 0.f, 0.f};
            #pragma unroll
            for (int kb = 0; kb < 4; ++kb) {
                a1a[nt] = __builtin_amdgcn_mfma_f32_16x16x32_bf16(fhh1[nt][kb], f1[kb], a1a[nt], 0, 0, 0);
                a1b[nt] = __builtin_amdgcn_mfma_f32_16x16x32_bf16(fih1[nt][kb], f0[kb], a1b[nt], 0, 0, 0);
            }
        }
        if (W == 0) {
            f32x4 aL = {bd0, bd1, 0.f, 0.f};
            #pragma unroll
            for (int kb = 0; kb < 4; ++kb)
                aL = __builtin_amdgcn_mfma_f32_16x16x32_bf16(fwd[kb], f1[kb], aL, 0, 0, 0);
            if (q == 0)
                sLd[126 * 17 + c] = bmPrev ? (aL[0] - aL[1]) : (aL[1] - aL[0]);
        }
        f32x4 a1[4];
        #pragma unroll
        for (int nt = 0; nt < 4; ++nt)
            a1[nt] = a1a[nt] + a1b[nt];
        storeL(sH1[1], a1);             // h1(127)
        __syncthreads();
    }
    // ---- i = 129: logits(127), wave 1 ----
    if (W == 1) {
        f32x4 aL = {bd0, bd1, 0.f, 0.f};
        #pragma unroll
        for (int kb = 0; kb < 4; ++kb) {
            bf16x8 f1 = *reinterpret_cast<const bf16x8*>(&sH1[1][ra[kb]]);
            aL = __builtin_amdgcn_mfma_f32_16x16x32_bf16(fwd[kb], f1, aL, 0, 0, 0);
        }
        if (q == 0) {
            const bool bit = (mw[3] >> 31) & 1u;
            sLd[127 * 17 + c] = bit ? (aL[0] - aL[1]) : (aL[1] - aL[0]);
        }
    }
    __syncthreads();

    // ---- final: lp(s) = sum_t -log(1 + exp(diff_t)); 8 lanes per sample ----
    {
        const int s = tid >> 3;         // sample 0..15
        const int k = tid & 7;          // 8-way split of 128 steps
        float acc = 0.0f;
        #pragma unroll
        for (int j = 0; j < 16; ++j) {
            const float x = sLd[(j * 8 + k) * 17 + s];
            const float ed = __builtin_exp2f(x * 1.4426950408889634f);
            acc -= 0.6931471805599453f * __builtin_log2f(1.0f + ed);
        }
        #pragma unroll
        for (int off = 1; off < 8; off <<= 1)
            acc += __shfl_xor(acc, off, 64);
        if (k == 0)
            out[b0 + s] = acc;
    }
}

extern "C" void kernel_launch(void* const* d_in, const int* in_sizes, int n_in,
                              void* d_out, int out_size, void* d_ws, size_t ws_size,
                              hipStream_t stream) {
    rnn_wf_kernel<<<NBLK, NTHR, 0, stream>>>(
        (const float*)d_in[0],  // samples
        (const float*)d_in[1],  // W_ih0
        (const float*)d_in[2],  // b_ih0
        (const float*)d_in[3],  // W_hh0
        (const float*)d_in[4],  // b_hh0
        (const float*)d_in[5],  // W_ih1
        (const float*)d_in[6],  // b_ih1
        (const float*)d_in[7],  // W_hh1
        (const float*)d_in[8],  // b_hh1
        (const float*)d_in[9],  // W_dense
        (const float*)d_in[10], // b_dense
        (float*)d_out);
}

// Round 10
// 260.903 us; speedup vs baseline: 1.2398x; 1.2398x over previous
//
#include <hip/hip_runtime.h>
#include <hip/hip_bf16.h>

// RNN wavefunction log-prob: N=128, B=8192, H=128, D=2 (one-hot). f32 in/out.
// R10: 256 blocks x 512 threads (8 waves), 1 block/CU, MB=32 samples/block
// as TWO independent m-tiles per wave -> 2x independent work between
// barriers (R8 post-mortem: 42% of cycles were barrier-phase-lock stall).
// Wave owns 16 cols (48 weight VGPRs, no spill). Logits duty rotates over
// waves per m-tile; log1pexp inline on duty wave, accumulated in registers.

#define NSTEP 128
#define BTOT  8192
#define HID   128
#define MB    32
#define NBLK  (BTOT / MB)   // 256
#define NTHR  512
#define MOFF  (16 * HID)    // halfword offset between m-tiles

typedef __attribute__((ext_vector_type(8))) short bf16x8;
typedef __attribute__((ext_vector_type(4))) float f32x4;
typedef __attribute__((ext_vector_type(2))) float f32x2;
typedef __attribute__((ext_vector_type(2))) unsigned uint32x2;

__device__ __forceinline__ short f2bf(float v) {
    unsigned u = __builtin_bit_cast(unsigned, v);
    u += 0x7FFFu + ((u >> 16) & 1u);
    return (short)(u >> 16);
}
__device__ __forceinline__ unsigned cvt2bf(float a, float b) {
    __hip_bfloat162 h2 = __float22bfloat162_rn(make_float2(a, b));
    unsigned u; __builtin_memcpy(&u, &h2, sizeof(u));
    return u;
}
// tanh on a pair: 2 exp + ONE rcp (shared via rcp(d0*d1))
__device__ __forceinline__ f32x2 tanh2(f32x2 x) {
    f32x2 z = x * 2.885390081777927f;            // 2x*log2(e)
    float e0 = __builtin_exp2f(z.x);
    float e1 = __builtin_exp2f(z.y);
    f32x2 d = {e0 + 1.0f, e1 + 1.0f};
    float r = __builtin_amdgcn_rcpf(d.x * d.y);
    f32x2 inv = {r * d.y, r * d.x};
    return inv * -2.0f + 1.0f;
}

__global__ __launch_bounds__(NTHR, 2) void rnn_wf_kernel(
    const float* __restrict__ samples,  // (128, 8192, 2)
    const float* __restrict__ Wih0,     // (128, 2)
    const float* __restrict__ bih0,     // (128,)
    const float* __restrict__ Whh0,     // (128, 128)
    const float* __restrict__ bhh0,     // (128,)
    const float* __restrict__ Wih1,     // (128, 128)
    const float* __restrict__ bih1,     // (128,)
    const float* __restrict__ Whh1,     // (128, 128)
    const float* __restrict__ bhh1,     // (128,)
    const float* __restrict__ Wd,       // (2, 128)
    const float* __restrict__ bd,       // (2,)
    float* __restrict__ out)            // (1, 8192)
{
    __shared__ short sH0[2][MB * HID];  // 16 KB
    __shared__ short sH1[2][MB * HID];  // 16 KB
    __shared__ unsigned sMask[NSTEP];   // 32-bit mask per step (32 samples)
    __shared__ float sLp[8 * MB];       // per-wave partial log-probs

    const int tid  = threadIdx.x;
    const int b0   = blockIdx.x * MB;
    const int w    = tid >> 6;          // wave 0..7, owns n in [16w, 16w+16)
    const int lane = tid & 63;
    const int q    = lane >> 4;
    const int c    = lane & 15;

    // ---- decode one-hot -> per-step 32-bit masks ----
    if (tid < NSTEP) {
        unsigned msk = 0;
        #pragma unroll
        for (int m = 0; m < MB; ++m) {
            float e1 = samples[((size_t)tid * BTOT + b0 + m) * 2 + 1];
            if (e1 > 0.5f) msk |= (1u << m);
        }
        sMask[tid] = msk;
    }

    // ---- weights -> A-frags: lane holds W[16w+c][kb*32+q*8 .. +8] ----
    bf16x8 fhh0[4], fih1[4], fhh1[4];
    {
        const int nn = w * 16 + c;
        #pragma unroll
        for (int kb = 0; kb < 4; ++kb) {
            const int off = nn * HID + kb * 32 + q * 8;
            bf16x8 v0, v1, v2;
            #pragma unroll
            for (int j = 0; j < 8; ++j) {
                v0[j] = f2bf(Whh0[off + j]);
                v1[j] = f2bf(Wih1[off + j]);
                v2[j] = f2bf(Whh1[off + j]);
            }
            fhh0[kb] = v0; fih1[kb] = v1; fhh1[kb] = v2;
        }
    }
    bf16x8 fwd[4];                      // dense head rows 0,1; rows>=2 zero
    #pragma unroll
    for (int kb = 0; kb < 4; ++kb) {
        bf16x8 v;
        #pragma unroll
        for (int j = 0; j < 8; ++j)
            v[j] = (c < 2) ? f2bf(Wd[c * HID + kb * 32 + q * 8 + j]) : (short)0;
        fwd[kb] = v;
    }
    // ---- biases in registers: n = 16w + 4q + r ----
    f32x4 pA, pB, b1v, b0v;
    #pragma unroll
    for (int r = 0; r < 4; ++r) {
        const int n = w * 16 + q * 4 + r;
        const float bb = bih0[n] + bhh0[n];
        b0v[r] = bb;
        pA[r]  = bb + Wih0[n * 2 + 0];
        pB[r]  = bb + Wih0[n * 2 + 1];
        b1v[r] = bih1[n] + bhh1[n];
    }
    const float bd0 = bd[0], bd1 = bd[1];

    // ---- t-invariant LDS indices (halfwords), full-c XOR swizzle ----
    int ra[4];
    #pragma unroll
    for (int kb = 0; kb < 4; ++kb)
        ra[kb] = c * HID + (((kb * 4 + q) ^ c) << 3);
    const int wa = c * HID + (((2 * w + (q >> 1)) ^ c) << 3) + ((q & 1) << 2);

    __syncthreads();                    // sMask published

    // ---- per-lane mask words: sample c (mt0) and 16+c (mt1) ----
    unsigned mw0[4] = {0,0,0,0}, mw1[4] = {0,0,0,0};
    for (int t = 0; t < NSTEP; ++t) {
        const unsigned mk = sMask[t];
        mw0[t >> 5] |= ((mk >> c)        & 1u) << (t & 31);
        mw1[t >> 5] |= ((mk >> (16 + c)) & 1u) << (t & 31);
    }
    auto mbit = [&](const unsigned* mw, int t) -> bool {
        return (mw[t >> 5] >> (t & 31)) & 1u;
    };

    float lp0 = 0.0f, lp1 = 0.0f;       // duty partial sums (q==0 lanes)

    auto storeOne = [&](short* buf, int mt, const f32x4& a) {
        f32x2 t0 = tanh2((f32x2){a[0], a[1]});
        f32x2 t1 = tanh2((f32x2){a[2], a[3]});
        uint32x2 v = {cvt2bf(t0.x, t0.y), cvt2bf(t1.x, t1.y)};
        *reinterpret_cast<uint32x2*>(&buf[mt * MOFF + wa]) = v;
    };
    auto duty = [&](const bf16x8* f1m, const unsigned* mwm, int t, float& acc) {
        f32x4 aL = {bd0, bd1, 0.f, 0.f};
        #pragma unroll
        for (int kb = 0; kb < 4; ++kb)
            aL = __builtin_amdgcn_mfma_f32_16x16x32_bf16(fwd[kb], f1m[kb], aL, 0, 0, 0);
        const bool bit = mbit(mwm, t);
        const float diff = bit ? (aL[0] - aL[1]) : (aL[1] - aL[0]);
        const float ed = __builtin_exp2f(diff * 1.4426950408889634f);
        acc -= 0.6931471805599453f * __builtin_log2f(1.0f + ed);
    };

    // ---- i = 0: h0(0) = tanh(b0), both m-tiles ----
    storeOne(sH0[1], 0, b0v);
    storeOne(sH0[1], 1, b0v);
    __syncthreads();

    // ---- i = 1: h0(1), h1(0), both m-tiles ----
    {
        bf16x8 f0[2][4];
        #pragma unroll
        for (int mt = 0; mt < 2; ++mt)
            #pragma unroll
            for (int kb = 0; kb < 4; ++kb)
                f0[mt][kb] = *reinterpret_cast<const bf16x8*>(&sH0[1][mt * MOFF + ra[kb]]);
        f32x4 a0[2], a1[2];
        a0[0] = mbit(mw0, 0) ? pB : pA;
        a0[1] = mbit(mw1, 0) ? pB : pA;
        a1[0] = b1v; a1[1] = b1v;
        #pragma unroll
        for (int mt = 0; mt < 2; ++mt)
            #pragma unroll
            for (int kb = 0; kb < 4; ++kb) {
                a0[mt] = __builtin_amdgcn_mfma_f32_16x16x32_bf16(fhh0[kb], f0[mt][kb], a0[mt], 0, 0, 0);
                a1[mt] = __builtin_amdgcn_mfma_f32_16x16x32_bf16(fih1[kb], f0[mt][kb], a1[mt], 0, 0, 0);
            }
        #pragma unroll
        for (int mt = 0; mt < 2; ++mt) {
            storeOne(sH0[0], mt, a0[mt]);   // h0(1)
            storeOne(sH1[0], mt, a1[mt]);   // h1(0)
        }
        __syncthreads();
    }

    // ---- main: i = 2..127, one barrier per iteration ----
    auto stepMain = [&](int i, const short* r0, const short* r1,
                        short* w0b, short* w1b) {
        const int ip = i - 1;
        bf16x8 f0[2][4], f1[2][4];
        #pragma unroll
        for (int mt = 0; mt < 2; ++mt)
            #pragma unroll
            for (int kb = 0; kb < 4; ++kb) {
                f0[mt][kb] = *reinterpret_cast<const bf16x8*>(&r0[mt * MOFF + ra[kb]]);
                f1[mt][kb] = *reinterpret_cast<const bf16x8*>(&r1[mt * MOFF + ra[kb]]);
            }
        f32x4 a0[2], a1a[2], a1b[2];
        a0[0]  = mbit(mw0, ip) ? pB : pA;
        a0[1]  = mbit(mw1, ip) ? pB : pA;
        a1a[0] = b1v; a1a[1] = b1v;
        a1b[0] = {0.f,0.f,0.f,0.f}; a1b[1] = {0.f,0.f,0.f,0.f};
        #pragma unroll
        for (int mt = 0; mt < 2; ++mt)
            #pragma unroll
            for (int kb = 0; kb < 4; ++kb) {
                a0[mt]  = __builtin_amdgcn_mfma_f32_16x16x32_bf16(fhh0[kb], f0[mt][kb], a0[mt],  0, 0, 0);
                a1a[mt] = __builtin_amdgcn_mfma_f32_16x16x32_bf16(fhh1[kb], f1[mt][kb], a1a[mt], 0, 0, 0);
                a1b[mt] = __builtin_amdgcn_mfma_f32_16x16x32_bf16(fih1[kb], f0[mt][kb], a1b[mt], 0, 0, 0);
            }
        if (w == (i & 7))       duty(f1[0], mw0, i - 2, lp0);   // logits(i-2), mt0
        if (w == ((i + 4) & 7)) duty(f1[1], mw1, i - 2, lp1);   // logits(i-2), mt1
        #pragma unroll
        for (int mt = 0; mt < 2; ++mt) {
            storeOne(w0b, mt, a0[mt]);                  // h0(i)
            f32x4 a1 = a1a[mt] + a1b[mt];
            storeOne(w1b, mt, a1);                      // h1(i-1)
        }
        __syncthreads();
    };

    for (int i = 2; i < NSTEP; i += 2) {
        stepMain(i,     sH0[0], sH1[0], sH0[1], sH1[1]);
        stepMain(i + 1, sH0[1], sH1[1], sH0[0], sH1[0]);
    }

    // ---- i = 128: h1(127), logits(126) ----
    {
        bf16x8 f0[2][4], f1[2][4];
        #pragma unroll
        for (int mt = 0; mt < 2; ++mt)
            #pragma unroll
            for (int kb = 0; kb < 4; ++kb) {
                f0[mt][kb] = *reinterpret_cast<const bf16x8*>(&sH0[0][mt * MOFF + ra[kb]]);  // h0(127)
                f1[mt][kb] = *reinterpret_cast<const bf16x8*>(&sH1[0][mt * MOFF + ra[kb]]);  // h1(126)
            }
        f32x4 a1a[2], a1b[2];
        a1a[0] = b1v; a1a[1] = b1v;
        a1b[0] = {0.f,0.f,0.f,0.f}; a1b[1] = {0.f,0.f,0.f,0.f};
        #pragma unroll
        for (int mt = 0; mt < 2; ++mt)
            #pragma unroll
            for (int kb = 0; kb < 4; ++kb) {
                a1a[mt] = __builtin_amdgcn_mfma_f32_16x16x32_bf16(fhh1[kb], f1[mt][kb], a1a[mt], 0, 0, 0);
                a1b[mt] = __builtin_amdgcn_mfma_f32_16x16x32_bf16(fih1[kb], f0[mt][kb], a1b[mt], 0, 0, 0);
            }
        if (w == 0) duty(f1[0], mw0, 126, lp0);
        if (w == 4) duty(f1[1], mw1, 126, lp1);
        #pragma unroll
        for (int mt = 0; mt < 2; ++mt) {
            f32x4 a1 = a1a[mt] + a1b[mt];
            storeOne(sH1[1], mt, a1);                   // h1(127)
        }
        __syncthreads();
    }
    // ---- i = 129: logits(127) ----
    {
        if (w == 1) {
            bf16x8 f1[4];
            #pragma unroll
            for (int kb = 0; kb < 4; ++kb)
                f1[kb] = *reinterpret_cast<const bf16x8*>(&sH1[1][ra[kb]]);
            duty(f1, mw0, 127, lp0);
        }
        if (w == 5) {
            bf16x8 f1[4];
            #pragma unroll
            for (int kb = 0; kb < 4; ++kb)
                f1[kb] = *reinterpret_cast<const bf16x8*>(&sH1[1][MOFF + ra[kb]]);
            duty(f1, mw1, 127, lp1);
        }
    }

    // ---- reduce per-wave duty partials across waves ----
    if (q == 0) {
        sLp[w * MB + c]      = lp0;
        sLp[w * MB + 16 + c] = lp1;
    }
    __syncthreads();
    if (tid < MB) {
        float s = 0.0f;
        #pragma unroll
        for (int ww = 0; ww < 8; ++ww)
            s += sLp[ww * MB + tid];
        out[b0 + tid] = s;
    }
}

extern "C" void kernel_launch(void* const* d_in, const int* in_sizes, int n_in,
                              void* d_out, int out_size, void* d_ws, size_t ws_size,
                              hipStream_t stream) {
    rnn_wf_kernel<<<NBLK, NTHR, 0, stream>>>(
        (const float*)d_in[0],  // samples
        (const float*)d_in[1],  // W_ih0
        (const float*)d_in[2],  // b_ih0
        (const float*)d_in[3],  // W_hh0
        (const float*)d_in[4],  // b_hh0
        (const float*)d_in[5],  // W_ih1
        (const float*)d_in[6],  // b_ih1
        (const float*)d_in[7],  // W_hh1
        (const float*)d_in[8],  // b_hh1
        (const float*)d_in[9],  // W_dense
        (const float*)d_in[10], // b_dense
        (float*)d_out);
}